// Round 1
// baseline (106.073 us; speedup 1.0000x reference)
//
#include <hip/hip_runtime.h>
#include <math.h>

#define TPB 256
#define KX 4   // query points per thread

// For each point in A, partial min squared-distance over a chunk of B.
// dir (blockIdx.z): 0 = forward (A=P, B=T), 1 = backward (A=T, B=P).
__global__ __launch_bounds__(TPB) void chamfer_minsq(
    const float* __restrict__ P, int NP,
    const float* __restrict__ T, int NT,
    float* __restrict__ partF, float* __restrict__ partB,
    int YC)
{
    const int dir = blockIdx.z;
    const float* __restrict__ A = dir ? T : P;
    const float* __restrict__ B = dir ? P : T;
    const int NA = dir ? NT : NP;
    const int NB = dir ? NP : NT;
    float* __restrict__ part = dir ? partB : partF;

    const int tid = threadIdx.x;
    const int xbase = blockIdx.x * (TPB * KX);
    if (xbase >= NA) return;

    const int chunk = (NB + YC - 1) / YC;
    const int y0 = blockIdx.y * chunk;
    const int y1 = min(y0 + chunk, NB);

    float ax[KX], ay[KX], az[KX], m[KX];
#pragma unroll
    for (int k = 0; k < KX; k++) {
        int xi = xbase + k * TPB + tid;
        int xc = xi < NA ? xi : NA - 1;
        ax[k] = A[3 * xc + 0];
        ay[k] = A[3 * xc + 1];
        az[k] = A[3 * xc + 2];
        m[k] = 3.4e38f;
    }

    int y = y0;
    const int yend2 = y0 + ((y1 - y0) & ~1);
#pragma unroll 2
    for (; y < yend2; y += 2) {
        // wave-uniform addresses -> scalar loads on the scalar pipe
        float bx0 = B[3 * y + 0], by0 = B[3 * y + 1], bz0 = B[3 * y + 2];
        float bx1 = B[3 * y + 3], by1 = B[3 * y + 4], bz1 = B[3 * y + 5];
#pragma unroll
        for (int k = 0; k < KX; k++) {
            float dx0 = ax[k] - bx0, dy0 = ay[k] - by0, dz0 = az[k] - bz0;
            float d0  = dx0 * dx0 + dy0 * dy0 + dz0 * dz0;
            float dx1 = ax[k] - bx1, dy1 = ay[k] - by1, dz1 = az[k] - bz1;
            float d1  = dx1 * dx1 + dy1 * dy1 + dz1 * dz1;
            m[k] = fminf(m[k], fminf(d0, d1));   // -> v_min3_f32
        }
    }
    for (; y < y1; y++) {
        float bx = B[3 * y + 0], by = B[3 * y + 1], bz = B[3 * y + 2];
#pragma unroll
        for (int k = 0; k < KX; k++) {
            float dx = ax[k] - bx, dy = ay[k] - by, dz = az[k] - bz;
            m[k] = fminf(m[k], dx * dx + dy * dy + dz * dz);
        }
    }

#pragma unroll
    for (int k = 0; k < KX; k++) {
        int xi = xbase + k * TPB + tid;
        if (xi < NA) part[(size_t)blockIdx.y * NA + xi] = m[k];
    }
}

// Min-reduce partials across chunks, sqrt, scale by 1/N, sum into *out.
__global__ __launch_bounds__(TPB) void chamfer_reduce(
    const float* __restrict__ partF, int NP,
    const float* __restrict__ partB, int NT,
    int YC, float scaleF, float scaleB, float* __restrict__ out)
{
    const int gid = blockIdx.x * TPB + threadIdx.x;
    float val = 0.f;
    if (gid < NP) {
        float mn = 3.4e38f;
        for (int c = 0; c < YC; c++) mn = fminf(mn, partF[(size_t)c * NP + gid]);
        val = sqrtf(fmaxf(mn, 0.f)) * scaleF;
    } else if (gid < NP + NT) {
        const int i = gid - NP;
        float mn = 3.4e38f;
        for (int c = 0; c < YC; c++) mn = fminf(mn, partB[(size_t)c * NT + i]);
        val = sqrtf(fmaxf(mn, 0.f)) * scaleB;
    }

    // wave (64-lane) reduction, then cross-wave via LDS
#pragma unroll
    for (int off = 32; off > 0; off >>= 1) val += __shfl_down(val, off);
    __shared__ float red[TPB / 64];
    const int lane = threadIdx.x & 63;
    const int w = threadIdx.x >> 6;
    if (lane == 0) red[w] = val;
    __syncthreads();
    if (threadIdx.x == 0) {
        float s = 0.f;
#pragma unroll
        for (int i = 0; i < TPB / 64; i++) s += red[i];
        atomicAdd(out, s);
    }
}

extern "C" void kernel_launch(void* const* d_in, const int* in_sizes, int n_in,
                              void* d_out, int out_size, void* d_ws, size_t ws_size,
                              hipStream_t stream) {
    const float* P = (const float*)d_in[0];
    const float* T = (const float*)d_in[1];
    const int NP = in_sizes[0] / 3;
    const int NT = in_sizes[1] / 3;
    float* out = (float*)d_out;

    // partials: [YC][NP] fwd + [YC][NT] bwd in workspace; shrink YC if needed
    int YC = 32;
    while (YC > 1 && (size_t)YC * (size_t)(NP + NT) * sizeof(float) > ws_size) YC >>= 1;
    float* partF = (float*)d_ws;
    float* partB = partF + (size_t)YC * NP;

    const int NAmax = NP > NT ? NP : NT;
    const int gx = (NAmax + TPB * KX - 1) / (TPB * KX);
    dim3 grid(gx, YC, 2);
    chamfer_minsq<<<grid, TPB, 0, stream>>>(P, NP, T, NT, partF, partB, YC);

    hipMemsetAsync(d_out, 0, sizeof(float), stream);

    const int rblocks = (NP + NT + TPB - 1) / TPB;
    chamfer_reduce<<<rblocks, TPB, 0, stream>>>(partF, NP, partB, NT, YC,
                                                1.0f / (float)NP, 1.0f / (float)NT, out);
}

// Round 2
// 77.947 us; speedup vs baseline: 1.3608x; 1.3608x over previous
//
#include <hip/hip_runtime.h>
#include <math.h>

typedef float v2f __attribute__((ext_vector_type(2)));

#define TPB 256
#define KX 4   // query points per thread

// Stage B sets as pair-entries of 8 floats: {-2x0,-2x1,-2y0,-2y1,-2z0,-2z1,c0,c1}
// where c = |b|^2. Odd N: last pair duplicates the final point (min unaffected).
__global__ __launch_bounds__(256) void chamfer_stage(
    const float* __restrict__ P, int NP, const float* __restrict__ T, int NT,
    float* __restrict__ SP, float* __restrict__ ST)
{
    const int NPp = (NP + 1) / 2, NTp = (NT + 1) / 2;
    const int total = NPp + NTp;
    for (int pe = blockIdx.x * blockDim.x + threadIdx.x; pe < total;
         pe += gridDim.x * blockDim.x) {
        const float* S; float* D; int n, j;
        if (pe < NPp) { S = P; D = SP; n = NP; j = pe; }
        else          { S = T; D = ST; n = NT; j = pe - NPp; }
        const int i0 = 2 * j;
        const int i1 = (2 * j + 1 < n) ? (2 * j + 1) : (n - 1);
        const float x0 = S[3*i0], y0 = S[3*i0+1], z0 = S[3*i0+2];
        const float x1 = S[3*i1], y1 = S[3*i1+1], z1 = S[3*i1+2];
        float4* dst = (float4*)(D + (size_t)8 * j);
        dst[0] = make_float4(-2.f*x0, -2.f*x1, -2.f*y0, -2.f*y1);
        dst[1] = make_float4(-2.f*z0, -2.f*z1,
                             x0*x0 + y0*y0 + z0*z0,
                             x1*x1 + y1*y1 + z1*z1);
    }
}

// For each query point a in A: partial min over a chunk of staged B of
// t = c - 2 a.b ; partial written = a^2 + min(t)  (= min d^2 for the chunk).
// dir (blockIdx.z): 0 = forward (A=P, B=T), 1 = backward (A=T, B=P).
__global__ __launch_bounds__(TPB, 6) void chamfer_minsq(
    const float* __restrict__ P, int NP,
    const float* __restrict__ T, int NT,
    const float* __restrict__ SP, const float* __restrict__ ST,
    float* __restrict__ partF, float* __restrict__ partB, int YC)
{
    const int dir = blockIdx.z;
    const float* __restrict__ A  = dir ? T : P;
    const float* __restrict__ Bs = dir ? SP : ST;   // staged opposite set
    const int NA = dir ? NT : NP;
    const int NB = dir ? NP : NT;
    float* __restrict__ part = dir ? partB : partF;

    const int tid = threadIdx.x;
    const int xbase = blockIdx.x * (TPB * KX);
    if (xbase >= NA) return;

    const int NBp = (NB + 1) / 2;                 // pair-entry count
    const int chunkp = (NBp + YC - 1) / YC;
    const int p0 = blockIdx.y * chunkp;
    const int p1 = min(p0 + chunkp, NBp);

    v2f axp[KX], ayp[KX], azp[KX];
    float m[KX], a2[KX];
#pragma unroll
    for (int k = 0; k < KX; k++) {
        const int xi = xbase + k * TPB + tid;
        const int xc = xi < NA ? xi : NA - 1;
        const float ax = A[3*xc], ay = A[3*xc+1], az = A[3*xc+2];
        axp[k] = (v2f){ax, ax};
        ayp[k] = (v2f){ay, ay};
        azp[k] = (v2f){az, az};
        a2[k] = ax*ax + ay*ay + az*az;
        m[k] = 3.4e38f;
    }

    int j = p0;
#pragma unroll 1
    for (; j + 2 <= p1; j += 2) {
        const float* bp = Bs + (size_t)j * 8;     // wave-uniform -> s_load
        const v2f mx0 = *(const v2f*)(bp + 0);
        const v2f my0 = *(const v2f*)(bp + 2);
        const v2f mz0 = *(const v2f*)(bp + 4);
        const v2f c0v = *(const v2f*)(bp + 6);
        const v2f mx1 = *(const v2f*)(bp + 8);
        const v2f my1 = *(const v2f*)(bp + 10);
        const v2f mz1 = *(const v2f*)(bp + 12);
        const v2f c1v = *(const v2f*)(bp + 14);
#pragma unroll
        for (int k = 0; k < KX; k++) {
            v2f t0, t1;
            asm("v_pk_fma_f32 %0, %1, %2, %3" : "=v"(t0) : "v"(azp[k]), "s"(mz0), "v"(c0v));
            asm("v_pk_fma_f32 %0, %1, %2, %0" : "+v"(t0) : "v"(ayp[k]), "s"(my0));
            asm("v_pk_fma_f32 %0, %1, %2, %0" : "+v"(t0) : "v"(axp[k]), "s"(mx0));
            asm("v_min3_f32 %0, %0, %1, %2"   : "+v"(m[k]) : "v"(t0.x), "v"(t0.y));
            asm("v_pk_fma_f32 %0, %1, %2, %3" : "=v"(t1) : "v"(azp[k]), "s"(mz1), "v"(c1v));
            asm("v_pk_fma_f32 %0, %1, %2, %0" : "+v"(t1) : "v"(ayp[k]), "s"(my1));
            asm("v_pk_fma_f32 %0, %1, %2, %0" : "+v"(t1) : "v"(axp[k]), "s"(mx1));
            asm("v_min3_f32 %0, %0, %1, %2"   : "+v"(m[k]) : "v"(t1.x), "v"(t1.y));
        }
    }
    for (; j < p1; j++) {   // odd-count tail
        const float* bp = Bs + (size_t)j * 8;
        const v2f mx = *(const v2f*)(bp + 0);
        const v2f my = *(const v2f*)(bp + 2);
        const v2f mz = *(const v2f*)(bp + 4);
        const v2f cv = *(const v2f*)(bp + 6);
#pragma unroll
        for (int k = 0; k < KX; k++) {
            v2f t;
            asm("v_pk_fma_f32 %0, %1, %2, %3" : "=v"(t) : "v"(azp[k]), "s"(mz), "v"(cv));
            asm("v_pk_fma_f32 %0, %1, %2, %0" : "+v"(t) : "v"(ayp[k]), "s"(my));
            asm("v_pk_fma_f32 %0, %1, %2, %0" : "+v"(t) : "v"(axp[k]), "s"(mx));
            asm("v_min3_f32 %0, %0, %1, %2"   : "+v"(m[k]) : "v"(t.x), "v"(t.y));
        }
    }

#pragma unroll
    for (int k = 0; k < KX; k++) {
        const int xi = xbase + k * TPB + tid;
        if (xi < NA) part[(size_t)blockIdx.y * NA + xi] = a2[k] + m[k];
    }
}

// Min-reduce partial d^2 across chunks, sqrt, scale by 1/N, sum into *out.
__global__ __launch_bounds__(TPB) void chamfer_reduce(
    const float* __restrict__ partF, int NP,
    const float* __restrict__ partB, int NT,
    int YC, float scaleF, float scaleB, float* __restrict__ out)
{
    const int gid = blockIdx.x * TPB + threadIdx.x;
    float val = 0.f;
    if (gid < NP) {
        float mn = 3.4e38f;
        for (int c = 0; c < YC; c++) mn = fminf(mn, partF[(size_t)c * NP + gid]);
        val = sqrtf(fmaxf(mn, 0.f)) * scaleF;
    } else if (gid < NP + NT) {
        const int i = gid - NP;
        float mn = 3.4e38f;
        for (int c = 0; c < YC; c++) mn = fminf(mn, partB[(size_t)c * NT + i]);
        val = sqrtf(fmaxf(mn, 0.f)) * scaleB;
    }

#pragma unroll
    for (int off = 32; off > 0; off >>= 1) val += __shfl_down(val, off);
    __shared__ float red[TPB / 64];
    const int lane = threadIdx.x & 63;
    const int w = threadIdx.x >> 6;
    if (lane == 0) red[w] = val;
    __syncthreads();
    if (threadIdx.x == 0) {
        float s = 0.f;
#pragma unroll
        for (int i = 0; i < TPB / 64; i++) s += red[i];
        atomicAdd(out, s);
    }
}

extern "C" void kernel_launch(void* const* d_in, const int* in_sizes, int n_in,
                              void* d_out, int out_size, void* d_ws, size_t ws_size,
                              hipStream_t stream) {
    const float* P = (const float*)d_in[0];
    const float* T = (const float*)d_in[1];
    const int NP = in_sizes[0] / 3;
    const int NT = in_sizes[1] / 3;
    float* out = (float*)d_out;

    const size_t NPp = (size_t)(NP + 1) / 2;
    const size_t NTp = (size_t)(NT + 1) / 2;
    const size_t stagedFloats = (NPp + NTp) * 8;

    int YC = 64;
    while (YC > 1 &&
           (stagedFloats + (size_t)YC * (size_t)(NP + NT)) * sizeof(float) > ws_size)
        YC >>= 1;

    float* SP    = (float*)d_ws;
    float* ST    = SP + NPp * 8;
    float* partF = ST + NTp * 8;
    float* partB = partF + (size_t)YC * NP;

    chamfer_stage<<<64, 256, 0, stream>>>(P, NP, T, NT, SP, ST);

    const int NAmax = NP > NT ? NP : NT;
    const int gx = (NAmax + TPB * KX - 1) / (TPB * KX);
    dim3 grid(gx, YC, 2);
    chamfer_minsq<<<grid, TPB, 0, stream>>>(P, NP, T, NT, SP, ST, partF, partB, YC);

    hipMemsetAsync(d_out, 0, sizeof(float), stream);

    const int rblocks = (NP + NT + TPB - 1) / TPB;
    chamfer_reduce<<<rblocks, TPB, 0, stream>>>(partF, NP, partB, NT, YC,
                                                1.0f / (float)NP, 1.0f / (float)NT, out);
}

// Round 3
// 67.931 us; speedup vs baseline: 1.5615x; 1.1474x over previous
//
#include <hip/hip_runtime.h>
#include <math.h>

typedef float v2f __attribute__((ext_vector_type(2)));
typedef float v4f __attribute__((ext_vector_type(4)));

#define TPB 256
#define KX 8        // query points per thread
#define PEPASS 256  // pair-entries staged in LDS per pass (8 KB)

// For each query point a in A: partial min over a chunk of B of
// t = c - 2 a.b (c=|b|^2); partial written = a^2 + min(t) = min d^2.
// B chunk is staged in LDS as pair-entries {-2x0,-2x1,-2y0,-2y1},{-2z0,-2z1,c0,c1}.
// dir (blockIdx.z): 0 = forward (A=P, B=T), 1 = backward (A=T, B=P).
__global__ __launch_bounds__(TPB, 4) void chamfer_minsq(
    const float* __restrict__ P, int NP,
    const float* __restrict__ T, int NT,
    float* __restrict__ partF, float* __restrict__ partB, int YC)
{
    const int dir = blockIdx.z;
    const float* __restrict__ A = dir ? T : P;
    const float* __restrict__ B = dir ? P : T;
    const int NA = dir ? NT : NP;
    const int NB = dir ? NP : NT;
    float* __restrict__ part = dir ? partB : partF;

    const int tid = threadIdx.x;
    const int xbase = blockIdx.x * (TPB * KX);
    if (xbase >= NA) return;

    const int NBp = (NB + 1) >> 1;               // pair-entry count
    const int chunkp = (NBp + YC - 1) / YC;
    const int p0 = blockIdx.y * chunkp;
    const int p1 = min(p0 + chunkp, NBp);

    if (p0 >= p1) {                               // empty chunk: neutral partials
#pragma unroll
        for (int k = 0; k < KX; k++) {
            const int xi = xbase + k * TPB + tid;
            if (xi < NA) part[(size_t)blockIdx.y * NA + xi] = 3.4e38f;
        }
        return;
    }

    v2f axp[KX], ayp[KX], azp[KX];
    float m[KX], a2[KX];
#pragma unroll
    for (int k = 0; k < KX; k++) {
        const int xi = xbase + k * TPB + tid;
        const int xc = xi < NA ? xi : NA - 1;     // duplicate query, harmless
        const float ax = A[3*xc], ay = A[3*xc+1], az = A[3*xc+2];
        axp[k] = (v2f){ax, ax};
        ayp[k] = (v2f){ay, ay};
        azp[k] = (v2f){az, az};
        a2[k] = ax*ax + ay*ay + az*az;
        m[k] = 3.4e38f;
    }

    __shared__ v4f lds[2 * PEPASS];               // 8 KB

    for (int base = p0; base < p1; base += PEPASS) {
        const int npe = min(PEPASS, p1 - base);

        // cooperative stage: raw B -> transformed pair-entries in LDS
        for (int t = tid; t < npe; t += TPB) {
            const int j = base + t;
            const int i0 = 2 * j;
            const int i1 = min(2 * j + 1, NB - 1);    // odd NB: duplicate last
            const float x0 = B[3*i0], y0 = B[3*i0+1], z0 = B[3*i0+2];
            const float x1 = B[3*i1], y1 = B[3*i1+1], z1 = B[3*i1+2];
            lds[2*t]   = (v4f){-2.f*x0, -2.f*x1, -2.f*y0, -2.f*y1};
            lds[2*t+1] = (v4f){-2.f*z0, -2.f*z1,
                               x0*x0 + y0*y0 + z0*z0,
                               x1*x1 + y1*y1 + z1*z1};
        }
        __syncthreads();

#pragma unroll 4
        for (int jj = 0; jj < npe; ++jj) {
            const v4f q0 = lds[2*jj];                 // ds_read_b128 broadcast
            const v4f q1 = lds[2*jj + 1];
            const v2f mx = __builtin_shufflevector(q0, q0, 0, 1);
            const v2f my = __builtin_shufflevector(q0, q0, 2, 3);
            const v2f mz = __builtin_shufflevector(q1, q1, 0, 1);
            const v2f cv = __builtin_shufflevector(q1, q1, 2, 3);
#pragma unroll
            for (int k = 0; k < KX; k++) {
                v2f t;
                asm("v_pk_fma_f32 %0, %1, %2, %3" : "=v"(t) : "v"(azp[k]), "v"(mz), "v"(cv));
                asm("v_pk_fma_f32 %0, %1, %2, %0" : "+v"(t) : "v"(ayp[k]), "v"(my));
                asm("v_pk_fma_f32 %0, %1, %2, %0" : "+v"(t) : "v"(axp[k]), "v"(mx));
                asm("v_min3_f32 %0, %0, %1, %2"   : "+v"(m[k]) : "v"(t.x), "v"(t.y));
            }
        }
        __syncthreads();
    }

#pragma unroll
    for (int k = 0; k < KX; k++) {
        const int xi = xbase + k * TPB + tid;
        if (xi < NA) part[(size_t)blockIdx.y * NA + xi] = a2[k] + m[k];
    }
}

// Min-reduce partial d^2 across chunks, sqrt, scale by 1/N, sum into *out.
__global__ __launch_bounds__(TPB) void chamfer_reduce(
    const float* __restrict__ partF, int NP,
    const float* __restrict__ partB, int NT,
    int YC, float scaleF, float scaleB, float* __restrict__ out)
{
    const int gid = blockIdx.x * TPB + threadIdx.x;
    float val = 0.f;
    if (gid < NP) {
        float mn = 3.4e38f;
        for (int c = 0; c < YC; c++) mn = fminf(mn, partF[(size_t)c * NP + gid]);
        val = sqrtf(fmaxf(mn, 0.f)) * scaleF;
    } else if (gid < NP + NT) {
        const int i = gid - NP;
        float mn = 3.4e38f;
        for (int c = 0; c < YC; c++) mn = fminf(mn, partB[(size_t)c * NT + i]);
        val = sqrtf(fmaxf(mn, 0.f)) * scaleB;
    }

#pragma unroll
    for (int off = 32; off > 0; off >>= 1) val += __shfl_down(val, off);
    __shared__ float red[TPB / 64];
    const int lane = threadIdx.x & 63;
    const int w = threadIdx.x >> 6;
    if (lane == 0) red[w] = val;
    __syncthreads();
    if (threadIdx.x == 0) {
        float s = 0.f;
#pragma unroll
        for (int i = 0; i < TPB / 64; i++) s += red[i];
        atomicAdd(out, s);
    }
}

extern "C" void kernel_launch(void* const* d_in, const int* in_sizes, int n_in,
                              void* d_out, int out_size, void* d_ws, size_t ws_size,
                              hipStream_t stream) {
    const float* P = (const float*)d_in[0];
    const float* T = (const float*)d_in[1];
    const int NP = in_sizes[0] / 3;
    const int NT = in_sizes[1] / 3;
    float* out = (float*)d_out;

    int YC = 64;
    while (YC > 1 && (size_t)YC * (size_t)(NP + NT) * sizeof(float) > ws_size)
        YC >>= 1;

    float* partF = (float*)d_ws;
    float* partB = partF + (size_t)YC * NP;

    const int NAmax = NP > NT ? NP : NT;
    const int gx = (NAmax + TPB * KX - 1) / (TPB * KX);
    dim3 grid(gx, YC, 2);
    chamfer_minsq<<<grid, TPB, 0, stream>>>(P, NP, T, NT, partF, partB, YC);

    hipMemsetAsync(d_out, 0, sizeof(float), stream);

    const int rblocks = (NP + NT + TPB - 1) / TPB;
    chamfer_reduce<<<rblocks, TPB, 0, stream>>>(partF, NP, partB, NT, YC,
                                                1.0f / (float)NP, 1.0f / (float)NT, out);
}